// Round 11
// baseline (62.342 us; speedup 1.0000x reference)
//
#include <hip/hip_runtime.h>
#include <math.h>
#include <stdint.h>

#define NEGV -1e30f
typedef unsigned short u16;
typedef unsigned int u32;
typedef short bfx8 __attribute__((ext_vector_type(8)));
typedef float f32x4 __attribute__((ext_vector_type(4)));

constexpr int B_  = 16;
constexpr int CL  = 512;
constexpr int QL  = 64;
constexpr int H   = 768;
constexpr int OD  = 4 * H;     // 3072 output cols
constexpr int IT  = 16;        // i-rows per block in ka

// ws layout (float offsets)
constexpr size_t WS_QW     = 0;            // [1024]  qw[b,j] (incl b_q + b_cq)
constexpr size_t WS_ROWMAX = 1024;         // [8192]
constexpr size_t WS_PART   = 17408;        // [16*16*768]
constexpr size_t WS_QBF    = 422912;       // u16[16][4][24][64][8]  frag-major bf16(q*w_cq)
constexpr size_t WS_QTF    = 816128;       // u16[16][48][2][64][8]  frag-major bf16(q)^T

__device__ __forceinline__ u16 f2b(float x) {     // fp32 -> bf16 RTNE
  u32 u = __float_as_uint(x);
  u += 0x7FFFu + ((u >> 16) & 1u);
  return (u16)(u >> 16);
}
__device__ __forceinline__ float wredmax(float v) {
#pragma unroll
  for (int off = 32; off; off >>= 1) v = fmaxf(v, __shfl_xor(v, off));
  return v;
}
__device__ __forceinline__ float wredsum(float v) {
#pragma unroll
  for (int off = 32; off; off >>= 1) v += __shfl_xor(v, off);
  return v;
}
__device__ __forceinline__ void ntst4(float* p, float x, float y, float z, float w) {
  f32x4 v = {x, y, z, w};
  __builtin_nontemporal_store(v, (f32x4*)p);
}
__device__ __forceinline__ void ntst4v(float* p, float4 v) {
  ntst4(p, v.x, v.y, v.z, v.w);
}

// ---------------- prologue: qw + fragment-major qbF/qTF ----------------
__global__ __launch_bounds__(256) void k_qprep(const float* __restrict__ q,
                                               const float* __restrict__ w_cq,
                                               const float* __restrict__ w_q,
                                               const float* __restrict__ b_q,
                                               const float* __restrict__ b_cq,
                                               u16* __restrict__ qbF,
                                               u16* __restrict__ qTF,
                                               float* __restrict__ qw) {
  const int ch = blockIdx.x, bb = blockIdx.y, t = threadIdx.x;
  if (ch == 6) {   // qw[b,j] = q[b,j,:].w_q + b_q + b_cq  (4 threads per j-row)
    int j = t >> 2, qt = t & 3;
    const float* qr = q + ((size_t)bb * QL + j) * H;
    float s = 0.f;
#pragma unroll 8
    for (int p = 0; p < 48; ++p) {
      float4 v = *(const float4*)(qr + (qt * 48 + p) * 4);
      float4 w = *(const float4*)(w_q + (qt * 48 + p) * 4);
      s += v.x * w.x + v.y * w.y + v.z * w.z + v.w * w.w;
    }
    s += __shfl_xor(s, 1);
    s += __shfl_xor(s, 2);
    if (qt == 0) qw[bb * QL + j] = s + b_q[0] + b_cq[0];
    return;
  }
  __shared__ u16 tR[64 * 132], tS[64 * 132];
  const int d0 = ch * 128;
#pragma unroll
  for (int s2 = 0; s2 < 8; ++s2) {
    int idx = t + s2 * 256, j = idx >> 5, d4 = idx & 31;
    size_t go = ((size_t)(bb * QL + j)) * H + d0 + d4 * 4;
    float4 v = *(const float4*)(q + go);
    float4 w = *(const float4*)(w_cq + d0 + d4 * 4);
    uint2 raw, scl;
    raw.x = f2b(v.x) | ((u32)f2b(v.y) << 16);
    raw.y = f2b(v.z) | ((u32)f2b(v.w) << 16);
    scl.x = f2b(v.x * w.x) | ((u32)f2b(v.y * w.y) << 16);
    scl.y = f2b(v.z * w.z) | ((u32)f2b(v.w * w.w) << 16);
    *(uint2*)&tR[j * 132 + d4 * 4] = raw;
    *(uint2*)&tS[j * 132 + d4 * 4] = scl;
  }
  __syncthreads();
  {  // qbF fragments
    int l = t & 63, jt = t >> 6, lr = l & 15, lg = l >> 4;
#pragma unroll
    for (int kt = 0; kt < 4; ++kt) {
      u16 vals[8];
#pragma unroll
      for (int e = 0; e < 8; ++e)
        vals[e] = tS[(jt * 16 + lr) * 132 + kt * 32 + lg * 8 + e];
      uint4 pk;
      pk.x = vals[0] | ((u32)vals[1] << 16);
      pk.y = vals[2] | ((u32)vals[3] << 16);
      pk.z = vals[4] | ((u32)vals[5] << 16);
      pk.w = vals[6] | ((u32)vals[7] << 16);
      *(uint4*)(qbF + ((((size_t)bb * 4 + jt) * 24) + ch * 4 + kt) * 512 + l * 8) = pk;
    }
  }
  {  // qTF fragments
#pragma unroll
    for (int rep = 0; rep < 4; ++rep) {
      int idx = rep * 256 + t;
      int l = idx & 63, h = (idx >> 6) & 1, uul = idx >> 7;
      int lr = l & 15, lg = l >> 4;
      u16 vals[8];
#pragma unroll
      for (int e = 0; e < 8; ++e)
        vals[e] = tR[(h * 32 + lg * 8 + e) * 132 + uul * 16 + lr];
      uint4 pk;
      pk.x = vals[0] | ((u32)vals[1] << 16);
      pk.y = vals[2] | ((u32)vals[3] << 16);
      pk.z = vals[4] | ((u32)vals[5] << 16);
      pk.w = vals[6] | ((u32)vals[7] << 16);
      *(uint4*)(qTF + (((size_t)bb * 48 + ch * 8 + uul) * 2 + h) * 512 + l * 8) = pk;
    }
  }
}

// ---------------- main kernel ----------------
__global__ __launch_bounds__(256, 4) void ka(const float* __restrict__ c,
                                             const float* __restrict__ c_mask,
                                             const float* __restrict__ q_mask,
                                             const float* __restrict__ w_c,
                                             const float* __restrict__ b_c,
                                             const float* __restrict__ qw,
                                             const u16* __restrict__ qbF,
                                             const u16* __restrict__ qTF,
                                             float* __restrict__ rowmax,
                                             float* __restrict__ out) {
  __shared__ __align__(16) u16 cA[IT * H];   // 24 KB bf16 c tile (swizzled)
  __shared__ float sS[IT * 68];              // 4.3 KB
  __shared__ u16 aS[IT * 64];                // 2 KB

  const int t = threadIdx.x, lane = t & 63;
  const int wid = __builtin_amdgcn_readfirstlane(t >> 6);
  const int bb = blockIdx.y, i0 = blockIdx.x * IT;
  const int lr = lane & 15, lg = lane >> 4;
  const int sw = (lr & 7) << 4;

  const u16* qbp = qbF + (((size_t)bb * 4 + wid) * 24) * 512 + lane * 8;
  const u16* qtp = qTF + (size_t)bb * 49152 + lane * 8;

  // early-issue phase-1 B prefetch (independent of LDS staging)
  bfx8 qpf0 = *(const bfx8*)(qbp);
  bfx8 qpf1 = *(const bfx8*)(qbp + 512);

  // ---- stage c tile (16x768) -> bf16 swizzled LDS, fused cw = c.w_c
  float cwq = 0.f;
  {
    int row = t >> 4, c4b = t & 15;
    size_t cb0 = ((size_t)bb * CL + i0 + row) * H;
#pragma unroll
    for (int u = 0; u < 12; ++u) {
      int col4 = c4b + u * 16;
      float4 v = *(const float4*)(c + cb0 + col4 * 4);
      float4 w = *(const float4*)(w_c + col4 * 4);
      cwq += v.x * w.x + v.y * w.y + v.z * w.z + v.w * w.w;
      uint2 pk;
      pk.x = f2b(v.x) | ((u32)f2b(v.y) << 16);
      pk.y = f2b(v.z) | ((u32)f2b(v.w) << 16);
      int byte = row * 1536 + ((col4 * 8) ^ ((row & 7) << 4));
      *(uint2*)((char*)cA + byte) = pk;
    }
    cwq += __shfl_xor(cwq, 1);
    cwq += __shfl_xor(cwq, 2);
    cwq += __shfl_xor(cwq, 4);
    cwq += __shfl_xor(cwq, 8);   // 16 lanes of quarter g hold cw(row 4*wid+g)
  }
  const float qw_r = qw[bb * QL + lane];   // includes b_q + b_cq
  const float qm_r = q_mask[bb * QL + lane];
  const float bc = b_c[0];
  __syncthreads();

  // ---- phase 1: s' = c @ (q*w_cq)^T
  f32x4 acc0 = {0.f, 0.f, 0.f, 0.f}, acc1 = {0.f, 0.f, 0.f, 0.f};
  {
    const char* ap = (const char*)cA + lr * 1536;
    acc0 = __builtin_amdgcn_mfma_f32_16x16x32_bf16(
        *(const bfx8*)(ap + ((lg * 16) ^ sw)), qpf0, acc0, 0, 0, 0);
    acc1 = __builtin_amdgcn_mfma_f32_16x16x32_bf16(
        *(const bfx8*)(ap + ((64 + lg * 16) ^ sw)), qpf1, acc1, 0, 0, 0);
#pragma unroll
    for (int kt = 2; kt < 24; kt += 2) {
      bfx8 av0 = *(const bfx8*)(ap + ((kt * 64 + lg * 16) ^ sw));
      bfx8 av1 = *(const bfx8*)(ap + (((kt + 1) * 64 + lg * 16) ^ sw));
      bfx8 bv0 = *(const bfx8*)(qbp + kt * 512);
      bfx8 bv1 = *(const bfx8*)(qbp + (kt + 1) * 512);
      acc0 = __builtin_amdgcn_mfma_f32_16x16x32_bf16(av0, bv0, acc0, 0, 0, 0);
      acc1 = __builtin_amdgcn_mfma_f32_16x16x32_bf16(av1, bv1, acc1, 0, 0, 0);
    }
  }
  // prefetch first phase-3 B fragments before the softmax barriers
  bfx8 pf0 = *(const bfx8*)(qtp + (size_t)(wid * 12 + 0) * 1024);
  bfx8 pf1 = *(const bfx8*)(qtp + (size_t)(wid * 12 + 0) * 1024 + 512);
  bfx8 pf2 = *(const bfx8*)(qtp + (size_t)(wid * 12 + 1) * 1024);
  bfx8 pf3 = *(const bfx8*)(qtp + (size_t)(wid * 12 + 1) * 1024 + 512);
#pragma unroll
  for (int m = 0; m < 4; ++m)
    sS[(lg * 4 + m) * 68 + wid * 16 + lr] = acc0[m] + acc1[m];
  __syncthreads();

  // ---- phase 2: softmax over j (lane = j), rowmax, a -> bf16 LDS
#pragma unroll
  for (int rr = 0; rr < 4; ++rr) {
    int r = wid * 4 + rr;
    float s = sS[r * 68 + lane] + qw_r;
    float mraw = wredmax(s);
    float sm = (qm_r > 0.5f) ? s : NEGV;
    float mm = wredmax(sm);
    float p = __expf(sm - mm);
    float ps = wredsum(p);
    float a = p / ps;
    float cwr = __shfl(cwq, rr * 16);
    if (lane == 0) {
      float cmv = c_mask[bb * CL + i0 + r];
      rowmax[bb * CL + i0 + r] = (cmv > 0.5f) ? (mraw + cwr + bc) : NEGV;
    }
    int byte = r * 128 + ((lane * 2) ^ ((r & 7) << 4));
    *(u16*)((char*)aS + byte) = f2b(a);
  }
  __syncthreads();

  // ---- phase 3 (transposed): c2q^T = q^T @ a^T via swapped operands.
  bfx8 a0 = *(const bfx8*)((char*)aS + lr * 128 + ((lg * 16) ^ sw));
  bfx8 a1 = *(const bfx8*)((char*)aS + lr * 128 + ((64 + lg * 16) ^ sw));
  f32x4 o[12];
  {
    f32x4 v0 = {0.f, 0.f, 0.f, 0.f};
    v0 = __builtin_amdgcn_mfma_f32_16x16x32_bf16(pf0, a0, v0, 0, 0, 0);
    v0 = __builtin_amdgcn_mfma_f32_16x16x32_bf16(pf1, a1, v0, 0, 0, 0);
    o[0] = v0;
    f32x4 v1 = {0.f, 0.f, 0.f, 0.f};
    v1 = __builtin_amdgcn_mfma_f32_16x16x32_bf16(pf2, a0, v1, 0, 0, 0);
    v1 = __builtin_amdgcn_mfma_f32_16x16x32_bf16(pf3, a1, v1, 0, 0, 0);
    o[1] = v1;
  }
#pragma unroll
  for (int u = 2; u < 12; ++u) {
    int uu = wid * 12 + u;
    bfx8 b0 = *(const bfx8*)(qtp + (size_t)uu * 1024);
    bfx8 b1 = *(const bfx8*)(qtp + (size_t)uu * 1024 + 512);
    f32x4 v = {0.f, 0.f, 0.f, 0.f};
    v = __builtin_amdgcn_mfma_f32_16x16x32_bf16(b0, a0, v, 0, 0, 0);
    v = __builtin_amdgcn_mfma_f32_16x16x32_bf16(b1, a1, v, 0, 0, 0);
    o[u] = v;
  }

  // ---- direct epilogue: non-temporal streaming stores (out never re-read)
  {
    size_t grow = (size_t)bb * CL + i0 + lr;
    const float* crow = c + grow * H;
    float* ob = out + grow * OD;
#pragma unroll
    for (int u = 0; u < 12; ++u) {
      int d4 = (wid * 12 + u) * 16 + lg * 4;
      float4 cv = *(const float4*)(crow + d4);
      ntst4v(ob + d4, cv);
      ntst4(ob + H + d4, o[u][0], o[u][1], o[u][2], o[u][3]);
      ntst4(ob + 2 * H + d4, cv.x * o[u][0], cv.y * o[u][1],
            cv.z * o[u][2], cv.w * o[u][3]);
    }
  }
}

// ---------------- fused b_att softmax + q2c partials (16 splits x 32 rows) ----------------
__global__ __launch_bounds__(256) void kb(const float* __restrict__ rowmax,
                                          const float* __restrict__ c,
                                          float* __restrict__ part) {
  int s = blockIdx.x, b = blockIdx.y, t = threadIdx.x;
  __shared__ float red[8];
  __shared__ float ba[32];
  float v0 = rowmax[b * CL + t], v1 = rowmax[b * CL + t + 256];
  float m = wredmax(fmaxf(v0, v1));
  if ((t & 63) == 0) red[t >> 6] = m;
  __syncthreads();
  m = fmaxf(fmaxf(red[0], red[1]), fmaxf(red[2], red[3]));
  float p = __expf(v0 - m) + __expf(v1 - m);
  p = wredsum(p);
  if ((t & 63) == 0) red[4 + (t >> 6)] = p;
  __syncthreads();
  float ssum = red[4] + red[5] + red[6] + red[7];
  if (t < 32) ba[t] = __expf(rowmax[b * CL + s * 32 + t] - m) / ssum;
  __syncthreads();
  if (t < 192) {
    const float* cb = c + ((size_t)b * CL + s * 32) * H;
    float4 acc = make_float4(0.f, 0.f, 0.f, 0.f);
#pragma unroll 8
    for (int r = 0; r < 32; ++r) {
      float w = ba[r];
      float4 cv = *(const float4*)(cb + (size_t)r * H + t * 4);
      acc.x += w * cv.x; acc.y += w * cv.y; acc.z += w * cv.z; acc.w += w * cv.w;
    }
    *(float4*)(part + ((size_t)b * 16 + s) * H + t * 4) = acc;
  }
}

// ---------------- seg3: per-strip q2c reduce + c*q2c write ----------------
__global__ __launch_bounds__(256) void kc2(const float* __restrict__ part,
                                           const float* __restrict__ c,
                                           float* __restrict__ out) {
  __shared__ float4 redS[8][32];
  __shared__ float4 q2cS[32];
  const int b = blockIdx.y;
  const int s = blockIdx.x >> 4, rg = blockIdx.x & 15;
  const int t = threadIdx.x;
  const int grp = t >> 5, col4 = t & 31;
  float4 acc = make_float4(0.f, 0.f, 0.f, 0.f);
#pragma unroll
  for (int u = 0; u < 2; ++u) {
    float4 v = *(const float4*)(part + ((size_t)b * 16 + grp * 2 + u) * H +
                                s * 128 + col4 * 4);
    acc.x += v.x; acc.y += v.y; acc.z += v.z; acc.w += v.w;
  }
  redS[grp][col4] = acc;
  __syncthreads();
  if (t < 32) {
    float4 sum = redS[0][t];
#pragma unroll
    for (int g = 1; g < 8; ++g) {
      float4 v = redS[g][t];
      sum.x += v.x; sum.y += v.y; sum.z += v.z; sum.w += v.w;
    }
    q2cS[t] = sum;
  }
  __syncthreads();
  float4 gv = q2cS[col4];
  const int sub = t >> 5;
#pragma unroll
  for (int r2 = 0; r2 < 4; ++r2) {
    int row = rg * 32 + sub * 4 + r2;
    size_t grow = (size_t)b * CL + row;
    float4 cv = *(const float4*)(c + grow * H + s * 128 + col4 * 4);
    ntst4(out + grow * OD + 3 * H + s * 128 + col4 * 4,
          cv.x * gv.x, cv.y * gv.y, cv.z * gv.z, cv.w * gv.w);
  }
}

extern "C" void kernel_launch(void* const* d_in, const int* in_sizes, int n_in,
                              void* d_out, int out_size, void* d_ws, size_t ws_size,
                              hipStream_t stream) {
  const float* c      = (const float*)d_in[0];
  const float* q      = (const float*)d_in[1];
  const float* c_mask = (const float*)d_in[2];
  const float* q_mask = (const float*)d_in[3];
  const float* w_c    = (const float*)d_in[4];
  const float* b_c    = (const float*)d_in[5];
  const float* w_q    = (const float*)d_in[6];
  const float* b_q    = (const float*)d_in[7];
  const float* w_cq   = (const float*)d_in[8];
  const float* b_cq   = (const float*)d_in[9];
  float* out = (float*)d_out;
  float* ws  = (float*)d_ws;
  float* qw     = ws + WS_QW;
  float* rowmax = ws + WS_ROWMAX;
  float* part   = ws + WS_PART;
  u16*   qbF    = (u16*)(ws + WS_QBF);
  u16*   qTF    = (u16*)(ws + WS_QTF);

  k_qprep<<<dim3(7, B_), 256, 0, stream>>>(q, w_cq, w_q, b_q, b_cq, qbF, qTF, qw);
  ka<<<dim3(CL / IT, B_), 256, 0, stream>>>(c, c_mask, q_mask, w_c, b_c,
                                            qw, qbF, qTF, rowmax, out);
  kb<<<dim3(16, B_), 256, 0, stream>>>(rowmax, c, part);
  kc2<<<dim3(96, B_), 256, 0, stream>>>(part, c, out);
}

// Round 12
// 58.251 us; speedup vs baseline: 1.0702x; 1.0702x over previous
//
#include <hip/hip_runtime.h>
#include <math.h>
#include <stdint.h>

#define NEGV -1e30f
typedef unsigned short u16;
typedef unsigned int u32;
typedef short bfx8 __attribute__((ext_vector_type(8)));
typedef float f32x4 __attribute__((ext_vector_type(4)));

constexpr int B_  = 16;
constexpr int CL  = 512;
constexpr int QL  = 64;
constexpr int H   = 768;
constexpr int OD  = 4 * H;     // 3072 output cols
constexpr int IT  = 16;        // i-rows per block in ka

// ws layout (float offsets)
constexpr size_t WS_QW     = 0;            // [1024]  qw[b,j] (incl b_q + b_cq)
constexpr size_t WS_ROWMAX = 1024;         // [8192]
constexpr size_t WS_PART   = 17408;        // [16*16*768]
constexpr size_t WS_QBF    = 422912;       // u16[16][4][24][64][8]  frag-major bf16(q*w_cq)
constexpr size_t WS_QTF    = 816128;       // u16[16][48][2][64][8]  frag-major bf16(q)^T

__device__ __forceinline__ u16 f2b(float x) {     // fp32 -> bf16 RTNE
  u32 u = __float_as_uint(x);
  u += 0x7FFFu + ((u >> 16) & 1u);
  return (u16)(u >> 16);
}
__device__ __forceinline__ float wredmax(float v) {
#pragma unroll
  for (int off = 32; off; off >>= 1) v = fmaxf(v, __shfl_xor(v, off));
  return v;
}
__device__ __forceinline__ float wredsum(float v) {
#pragma unroll
  for (int off = 32; off; off >>= 1) v += __shfl_xor(v, off);
  return v;
}

// ---------------- prologue: qw + fragment-major qbF/qTF ----------------
__global__ __launch_bounds__(256) void k_qprep(const float* __restrict__ q,
                                               const float* __restrict__ w_cq,
                                               const float* __restrict__ w_q,
                                               const float* __restrict__ b_q,
                                               const float* __restrict__ b_cq,
                                               u16* __restrict__ qbF,
                                               u16* __restrict__ qTF,
                                               float* __restrict__ qw) {
  const int ch = blockIdx.x, bb = blockIdx.y, t = threadIdx.x;
  if (ch == 6) {   // qw[b,j] = q[b,j,:].w_q + b_q + b_cq  (4 threads per j-row)
    int j = t >> 2, qt = t & 3;
    const float* qr = q + ((size_t)bb * QL + j) * H;
    float s = 0.f;
#pragma unroll 8
    for (int p = 0; p < 48; ++p) {
      float4 v = *(const float4*)(qr + (qt * 48 + p) * 4);
      float4 w = *(const float4*)(w_q + (qt * 48 + p) * 4);
      s += v.x * w.x + v.y * w.y + v.z * w.z + v.w * w.w;
    }
    s += __shfl_xor(s, 1);
    s += __shfl_xor(s, 2);
    if (qt == 0) qw[bb * QL + j] = s + b_q[0] + b_cq[0];
    return;
  }
  __shared__ u16 tR[64 * 132], tS[64 * 132];
  const int d0 = ch * 128;
#pragma unroll
  for (int s2 = 0; s2 < 8; ++s2) {
    int idx = t + s2 * 256, j = idx >> 5, d4 = idx & 31;
    size_t go = ((size_t)(bb * QL + j)) * H + d0 + d4 * 4;
    float4 v = *(const float4*)(q + go);
    float4 w = *(const float4*)(w_cq + d0 + d4 * 4);
    uint2 raw, scl;
    raw.x = f2b(v.x) | ((u32)f2b(v.y) << 16);
    raw.y = f2b(v.z) | ((u32)f2b(v.w) << 16);
    scl.x = f2b(v.x * w.x) | ((u32)f2b(v.y * w.y) << 16);
    scl.y = f2b(v.z * w.z) | ((u32)f2b(v.w * w.w) << 16);
    *(uint2*)&tR[j * 132 + d4 * 4] = raw;
    *(uint2*)&tS[j * 132 + d4 * 4] = scl;
  }
  __syncthreads();
  {  // qbF fragments
    int l = t & 63, jt = t >> 6, lr = l & 15, lg = l >> 4;
#pragma unroll
    for (int kt = 0; kt < 4; ++kt) {
      u16 vals[8];
#pragma unroll
      for (int e = 0; e < 8; ++e)
        vals[e] = tS[(jt * 16 + lr) * 132 + kt * 32 + lg * 8 + e];
      uint4 pk;
      pk.x = vals[0] | ((u32)vals[1] << 16);
      pk.y = vals[2] | ((u32)vals[3] << 16);
      pk.z = vals[4] | ((u32)vals[5] << 16);
      pk.w = vals[6] | ((u32)vals[7] << 16);
      *(uint4*)(qbF + ((((size_t)bb * 4 + jt) * 24) + ch * 4 + kt) * 512 + l * 8) = pk;
    }
  }
  {  // qTF fragments
#pragma unroll
    for (int rep = 0; rep < 4; ++rep) {
      int idx = rep * 256 + t;
      int l = idx & 63, h = (idx >> 6) & 1, uul = idx >> 7;
      int lr = l & 15, lg = l >> 4;
      u16 vals[8];
#pragma unroll
      for (int e = 0; e < 8; ++e)
        vals[e] = tR[(h * 32 + lg * 8 + e) * 132 + uul * 16 + lr];
      uint4 pk;
      pk.x = vals[0] | ((u32)vals[1] << 16);
      pk.y = vals[2] | ((u32)vals[3] << 16);
      pk.z = vals[4] | ((u32)vals[5] << 16);
      pk.w = vals[6] | ((u32)vals[7] << 16);
      *(uint4*)(qTF + (((size_t)bb * 48 + ch * 8 + uul) * 2 + h) * 512 + l * 8) = pk;
    }
  }
}

// ---------------- main kernel ----------------
__global__ __launch_bounds__(256, 4) void ka(const float* __restrict__ c,
                                             const float* __restrict__ c_mask,
                                             const float* __restrict__ q_mask,
                                             const float* __restrict__ w_c,
                                             const float* __restrict__ b_c,
                                             const float* __restrict__ qw,
                                             const u16* __restrict__ qbF,
                                             const u16* __restrict__ qTF,
                                             float* __restrict__ rowmax,
                                             float* __restrict__ out) {
  __shared__ __align__(16) u16 cA[IT * H];   // 24 KB bf16 c tile (swizzled)
  __shared__ float sS[IT * 68];              // 4.3 KB
  __shared__ u16 aS[IT * 64];                // 2 KB

  const int t = threadIdx.x, lane = t & 63;
  const int wid = __builtin_amdgcn_readfirstlane(t >> 6);
  const int bb = blockIdx.y, i0 = blockIdx.x * IT;
  const int lr = lane & 15, lg = lane >> 4;
  const int sw = (lr & 7) << 4;

  const u16* qbp = qbF + (((size_t)bb * 4 + wid) * 24) * 512 + lane * 8;
  const u16* qtp = qTF + (size_t)bb * 49152 + lane * 8;

  // early-issue phase-1 B prefetch (independent of LDS staging)
  bfx8 qpf0 = *(const bfx8*)(qbp);
  bfx8 qpf1 = *(const bfx8*)(qbp + 512);

  // ---- stage c tile (16x768) -> bf16 swizzled LDS, fused cw = c.w_c
  float cwq = 0.f;
  {
    int row = t >> 4, c4b = t & 15;
    size_t cb0 = ((size_t)bb * CL + i0 + row) * H;
#pragma unroll
    for (int u = 0; u < 12; ++u) {
      int col4 = c4b + u * 16;
      float4 v = *(const float4*)(c + cb0 + col4 * 4);
      float4 w = *(const float4*)(w_c + col4 * 4);
      cwq += v.x * w.x + v.y * w.y + v.z * w.z + v.w * w.w;
      uint2 pk;
      pk.x = f2b(v.x) | ((u32)f2b(v.y) << 16);
      pk.y = f2b(v.z) | ((u32)f2b(v.w) << 16);
      int byte = row * 1536 + ((col4 * 8) ^ ((row & 7) << 4));
      *(uint2*)((char*)cA + byte) = pk;
    }
    cwq += __shfl_xor(cwq, 1);
    cwq += __shfl_xor(cwq, 2);
    cwq += __shfl_xor(cwq, 4);
    cwq += __shfl_xor(cwq, 8);   // 16 lanes of quarter g hold cw(row 4*wid+g)
  }
  const float qw_r = qw[bb * QL + lane];   // includes b_q + b_cq
  const float qm_r = q_mask[bb * QL + lane];
  const float bc = b_c[0];
  __syncthreads();

  // ---- phase 1: s' = c @ (q*w_cq)^T
  f32x4 acc0 = {0.f, 0.f, 0.f, 0.f}, acc1 = {0.f, 0.f, 0.f, 0.f};
  {
    const char* ap = (const char*)cA + lr * 1536;
    acc0 = __builtin_amdgcn_mfma_f32_16x16x32_bf16(
        *(const bfx8*)(ap + ((lg * 16) ^ sw)), qpf0, acc0, 0, 0, 0);
    acc1 = __builtin_amdgcn_mfma_f32_16x16x32_bf16(
        *(const bfx8*)(ap + ((64 + lg * 16) ^ sw)), qpf1, acc1, 0, 0, 0);
#pragma unroll
    for (int kt = 2; kt < 24; kt += 2) {
      bfx8 av0 = *(const bfx8*)(ap + ((kt * 64 + lg * 16) ^ sw));
      bfx8 av1 = *(const bfx8*)(ap + (((kt + 1) * 64 + lg * 16) ^ sw));
      bfx8 bv0 = *(const bfx8*)(qbp + kt * 512);
      bfx8 bv1 = *(const bfx8*)(qbp + (kt + 1) * 512);
      acc0 = __builtin_amdgcn_mfma_f32_16x16x32_bf16(av0, bv0, acc0, 0, 0, 0);
      acc1 = __builtin_amdgcn_mfma_f32_16x16x32_bf16(av1, bv1, acc1, 0, 0, 0);
    }
  }
  // prefetch first phase-3 B fragments before the softmax barriers
  bfx8 pf0 = *(const bfx8*)(qtp + (size_t)(wid * 12 + 0) * 1024);
  bfx8 pf1 = *(const bfx8*)(qtp + (size_t)(wid * 12 + 0) * 1024 + 512);
  bfx8 pf2 = *(const bfx8*)(qtp + (size_t)(wid * 12 + 1) * 1024);
  bfx8 pf3 = *(const bfx8*)(qtp + (size_t)(wid * 12 + 1) * 1024 + 512);
#pragma unroll
  for (int m = 0; m < 4; ++m)
    sS[(lg * 4 + m) * 68 + wid * 16 + lr] = acc0[m] + acc1[m];
  __syncthreads();

  // ---- phase 2: softmax over j (lane = j), rowmax, a -> bf16 LDS
#pragma unroll
  for (int rr = 0; rr < 4; ++rr) {
    int r = wid * 4 + rr;
    float s = sS[r * 68 + lane] + qw_r;
    float mraw = wredmax(s);
    float sm = (qm_r > 0.5f) ? s : NEGV;
    float mm = wredmax(sm);
    float p = __expf(sm - mm);
    float ps = wredsum(p);
    float a = p / ps;
    float cwr = __shfl(cwq, rr * 16);
    if (lane == 0) {
      float cmv = c_mask[bb * CL + i0 + r];
      rowmax[bb * CL + i0 + r] = (cmv > 0.5f) ? (mraw + cwr + bc) : NEGV;
    }
    int byte = r * 128 + ((lane * 2) ^ ((r & 7) << 4));
    *(u16*)((char*)aS + byte) = f2b(a);
  }
  __syncthreads();

  // ---- phase 3 (transposed): c2q^T = q^T @ a^T via swapped operands.
  bfx8 a0 = *(const bfx8*)((char*)aS + lr * 128 + ((lg * 16) ^ sw));
  bfx8 a1 = *(const bfx8*)((char*)aS + lr * 128 + ((64 + lg * 16) ^ sw));
  f32x4 o[12];
  {
    f32x4 v0 = {0.f, 0.f, 0.f, 0.f};
    v0 = __builtin_amdgcn_mfma_f32_16x16x32_bf16(pf0, a0, v0, 0, 0, 0);
    v0 = __builtin_amdgcn_mfma_f32_16x16x32_bf16(pf1, a1, v0, 0, 0, 0);
    o[0] = v0;
    f32x4 v1 = {0.f, 0.f, 0.f, 0.f};
    v1 = __builtin_amdgcn_mfma_f32_16x16x32_bf16(pf2, a0, v1, 0, 0, 0);
    v1 = __builtin_amdgcn_mfma_f32_16x16x32_bf16(pf3, a1, v1, 0, 0, 0);
    o[1] = v1;
  }
#pragma unroll
  for (int u = 2; u < 12; ++u) {
    int uu = wid * 12 + u;
    bfx8 b0 = *(const bfx8*)(qtp + (size_t)uu * 1024);
    bfx8 b1 = *(const bfx8*)(qtp + (size_t)uu * 1024 + 512);
    f32x4 v = {0.f, 0.f, 0.f, 0.f};
    v = __builtin_amdgcn_mfma_f32_16x16x32_bf16(b0, a0, v, 0, 0, 0);
    v = __builtin_amdgcn_mfma_f32_16x16x32_bf16(b1, a1, v, 0, 0, 0);
    o[u] = v;
  }

  // ---- direct epilogue: no LDS bounce, no barriers
  {
    size_t grow = (size_t)bb * CL + i0 + lr;
    const float* crow = c + grow * H;
    float* ob = out + grow * OD;
#pragma unroll
    for (int u = 0; u < 12; ++u) {
      int d4 = (wid * 12 + u) * 16 + lg * 4;
      float4 cv = *(const float4*)(crow + d4);
      float4 ov = make_float4(o[u][0], o[u][1], o[u][2], o[u][3]);
      *(float4*)(ob + d4) = cv;
      *(float4*)(ob + H + d4) = ov;
      *(float4*)(ob + 2 * H + d4) = make_float4(cv.x * ov.x, cv.y * ov.y,
                                                cv.z * ov.z, cv.w * ov.w);
    }
  }
}

// ---------------- fused b_att softmax + q2c partials (16 splits x 32 rows) ----------------
__global__ __launch_bounds__(256) void kb(const float* __restrict__ rowmax,
                                          const float* __restrict__ c,
                                          float* __restrict__ part) {
  int s = blockIdx.x, b = blockIdx.y, t = threadIdx.x;
  __shared__ float red[8];
  __shared__ float ba[32];
  float v0 = rowmax[b * CL + t], v1 = rowmax[b * CL + t + 256];
  float m = wredmax(fmaxf(v0, v1));
  if ((t & 63) == 0) red[t >> 6] = m;
  __syncthreads();
  m = fmaxf(fmaxf(red[0], red[1]), fmaxf(red[2], red[3]));
  float p = __expf(v0 - m) + __expf(v1 - m);
  p = wredsum(p);
  if ((t & 63) == 0) red[4 + (t >> 6)] = p;
  __syncthreads();
  float ssum = red[4] + red[5] + red[6] + red[7];
  if (t < 32) ba[t] = __expf(rowmax[b * CL + s * 32 + t] - m) / ssum;
  __syncthreads();
  if (t < 192) {
    const float* cb = c + ((size_t)b * CL + s * 32) * H;
    float4 acc = make_float4(0.f, 0.f, 0.f, 0.f);
#pragma unroll 8
    for (int r = 0; r < 32; ++r) {
      float w = ba[r];
      float4 cv = *(const float4*)(cb + (size_t)r * H + t * 4);
      acc.x += w * cv.x; acc.y += w * cv.y; acc.z += w * cv.z; acc.w += w * cv.w;
    }
    *(float4*)(part + ((size_t)b * 16 + s) * H + t * 4) = acc;
  }
}

// ---------------- seg3: per-strip q2c reduce + c*q2c write ----------------
__global__ __launch_bounds__(256) void kc2(const float* __restrict__ part,
                                           const float* __restrict__ c,
                                           float* __restrict__ out) {
  __shared__ float4 redS[8][32];
  __shared__ float4 q2cS[32];
  const int b = blockIdx.y;
  const int s = blockIdx.x >> 4, rg = blockIdx.x & 15;
  const int t = threadIdx.x;
  const int grp = t >> 5, col4 = t & 31;
  float4 acc = make_float4(0.f, 0.f, 0.f, 0.f);
#pragma unroll
  for (int u = 0; u < 2; ++u) {
    float4 v = *(const float4*)(part + ((size_t)b * 16 + grp * 2 + u) * H +
                                s * 128 + col4 * 4);
    acc.x += v.x; acc.y += v.y; acc.z += v.z; acc.w += v.w;
  }
  redS[grp][col4] = acc;
  __syncthreads();
  if (t < 32) {
    float4 sum = redS[0][t];
#pragma unroll
    for (int g = 1; g < 8; ++g) {
      float4 v = redS[g][t];
      sum.x += v.x; sum.y += v.y; sum.z += v.z; sum.w += v.w;
    }
    q2cS[t] = sum;
  }
  __syncthreads();
  float4 gv = q2cS[col4];
  const int sub = t >> 5;
#pragma unroll
  for (int r2 = 0; r2 < 4; ++r2) {
    int row = rg * 32 + sub * 4 + r2;
    size_t grow = (size_t)b * CL + row;
    float4 cv = *(const float4*)(c + grow * H + s * 128 + col4 * 4);
    *(float4*)(out + grow * OD + 3 * H + s * 128 + col4 * 4) =
        make_float4(cv.x * gv.x, cv.y * gv.y, cv.z * gv.z, cv.w * gv.w);
  }
}

extern "C" void kernel_launch(void* const* d_in, const int* in_sizes, int n_in,
                              void* d_out, int out_size, void* d_ws, size_t ws_size,
                              hipStream_t stream) {
  const float* c      = (const float*)d_in[0];
  const float* q      = (const float*)d_in[1];
  const float* c_mask = (const float*)d_in[2];
  const float* q_mask = (const float*)d_in[3];
  const float* w_c    = (const float*)d_in[4];
  const float* b_c    = (const float*)d_in[5];
  const float* w_q    = (const float*)d_in[6];
  const float* b_q    = (const float*)d_in[7];
  const float* w_cq   = (const float*)d_in[8];
  const float* b_cq   = (const float*)d_in[9];
  float* out = (float*)d_out;
  float* ws  = (float*)d_ws;
  float* qw     = ws + WS_QW;
  float* rowmax = ws + WS_ROWMAX;
  float* part   = ws + WS_PART;
  u16*   qbF    = (u16*)(ws + WS_QBF);
  u16*   qTF    = (u16*)(ws + WS_QTF);

  k_qprep<<<dim3(7, B_), 256, 0, stream>>>(q, w_cq, w_q, b_q, b_cq, qbF, qTF, qw);
  ka<<<dim3(CL / IT, B_), 256, 0, stream>>>(c, c_mask, q_mask, w_c, b_c,
                                            qw, qbF, qTF, rowmax, out);
  kb<<<dim3(16, B_), 256, 0, stream>>>(rowmax, c, part);
  kc2<<<dim3(96, B_), 256, 0, stream>>>(part, c, out);
}